// Round 9
// baseline (297.685 us; speedup 1.0000x reference)
//
#include <hip/hip_runtime.h>
#include <hip/hip_fp16.h>

// Self-attention B=8 S=2048 D=512, fp32-vs-bf16 input auto-detect.
// R9 = R8 + XCD-locality block swizzles (lin%8 -> XCD heuristic):
//   proj:   each XCD owns a 2 MB slice of x rows  (+1.5 MB WT < 4 MB L2)
//   scores: each XCD owns one batch (q,k slices L2-warm)
//   PV:     each XCD owns one batch (2 MB vT column slice L2-resident)
// Math bit-identical to R8 (only block->tile mapping changed).

typedef unsigned short u16;
typedef unsigned int u32;
typedef __attribute__((ext_vector_type(8))) _Float16 f16x8;
typedef __attribute__((ext_vector_type(16))) float f32x16;

#define S_LEN 2048
#define D_DIM 512
#define B_N 8

__device__ __forceinline__ u16 f2bf(float f) {
    u32 u = __float_as_uint(f);
    u32 r = u + 0x7FFFu + ((u >> 16) & 1u);   // RNE
    return (u16)(r >> 16);
}
__device__ __forceinline__ float bf2f(u16 h) {
    return __uint_as_float((u32)h << 16);
}
__device__ __forceinline__ u16 f2h(float f) {
    _Float16 h = (_Float16)f;                 // RNE
    return *(u16*)&h;
}
__device__ __forceinline__ void gl16(const u16* g, u16* l) {
    __builtin_amdgcn_global_load_lds(
        (const __attribute__((address_space(1))) void*)g,
        (__attribute__((address_space(3))) void*)l, 16, 0, 0);
}
__device__ __forceinline__ f32x16 mfma16(f16x8 a, f16x8 b, f32x16 c) {
    return __builtin_amdgcn_mfma_f32_32x32x16_f16(a, b, c, 0, 0, 0);
}

// ---- dtype detector ----
__global__ void detect_k(const u16* __restrict__ x, int* __restrict__ flag)
{
    int t = threadIdx.x;
    u16 u = x[2 * t];
    int e = (u >> 7) & 0xFF;
    int sane = (e == 0) || (e >= 110 && e <= 140);
    unsigned long long b = __ballot(sane);
    if (t == 0) *flag = (__popcll(b) >= 32) ? 1 : 0;
}

// ---- convert x to fp16 ----
__global__ __launch_bounds__(256) void cvt_x(
    const void* __restrict__ X, u16* __restrict__ xf,
    const int* __restrict__ flagp)
{
    const size_t i4 = ((size_t)blockIdx.x * 256 + threadIdx.x) * 4;
    float f[4];
    if (*flagp) {
        ushort4 u = *(const ushort4*)((const u16*)X + i4);
        f[0] = bf2f(u.x); f[1] = bf2f(u.y); f[2] = bf2f(u.z); f[3] = bf2f(u.w);
    } else {
        float4 ff = *(const float4*)((const float*)X + i4);
        f[0] = ff.x; f[1] = ff.y; f[2] = ff.z; f[3] = ff.w;
    }
    ushort4 h;
    h.x = f2h(f[0]); h.y = f2h(f[1]); h.z = f2h(f[2]); h.w = f2h(f[3]);
    *(ushort4*)(xf + i4) = h;
}

// ---- pack W^T concat (q|k|v) fp16: WT[n 0..1535][k 0..511] ----
__global__ __launch_bounds__(256) void pack_w(
    const void* __restrict__ Wq, const void* __restrict__ Wk, const void* __restrict__ Wv,
    u16* __restrict__ WT, const int* __restrict__ flagp)
{
    const int k = blockIdx.x;
    const int n = blockIdx.y * 256 + threadIdx.x;
    const void* W = n < 512 ? Wq : n < 1024 ? Wk : Wv;
    const int nc = n & 511;
    float f = *flagp ? bf2f(((const u16*)W)[(size_t)k * 512 + nc])
                     : ((const float*)W)[(size_t)k * 512 + nc];
    WT[(size_t)n * 512 + k] = f2h(f);
}

__global__ void pack_bias(
    const void* __restrict__ bq, const void* __restrict__ bk, const void* __restrict__ bv,
    float* __restrict__ bcat, const int* __restrict__ flagp)
{
    const int t = blockIdx.x * 256 + threadIdx.x;
    const void* b = t < 512 ? bq : t < 1024 ? bk : bv;
    const int i = t & 511;
    bcat[t] = *flagp ? bf2f(((const u16*)b)[i]) : ((const float*)b)[i];
}

// ---- unified fp16 BT-GEMM: C[M,N] = A[M,K] * B[N,K]^T ----
// 128x128 tile, BK=64. Staging: slot s of row r holds global chunk s^(r&7).
// EPI 0: fp32 C (scores). EPI 1: flag-dtyped C (out). EPI 2: proj q|k|vT +bias.
template <int EPI>
__global__ __launch_bounds__(256) void gemm_f16(
    const u16* __restrict__ A_, const u16* __restrict__ B_,
    void* __restrict__ Cp, const float* __restrict__ biasf,
    u16* __restrict__ Oq, u16* __restrict__ Ok, u16* __restrict__ OvT,
    const int* __restrict__ flagp,
    int K, int lda, int ldb, int ldc, long sA, long sB, long sC, long cbase)
{
    // ---- XCD-locality swizzle (lin%8 -> XCD heuristic; bijective remaps) ----
    int bx, by, bz;
    if (EPI == 2) {
        // grid (12,128,1): XCD i owns y in [16i,16i+16)
        const int lin = blockIdx.y * 12 + blockIdx.x;
        const int xcd = lin & 7, j = lin >> 3;            // j in 0..191
        by = xcd * 16 + j / 12;
        bx = j % 12;
        bz = 0;
    } else if (EPI == 0) {
        if (gridDim.z == 8) {                             // grid (16,16,8)
            const int lin = (blockIdx.z * 16 + blockIdx.y) * 16 + blockIdx.x;
            const int xcd = lin & 7, j = lin >> 3;        // j in 0..255
            bx = j & 15; by = (j >> 4) & 15; bz = xcd;    // XCD = batch
        } else { bx = blockIdx.x; by = blockIdx.y; bz = blockIdx.z; }
    } else {
        if (gridDim.z == 8) {                             // grid (4,16,8)
            const int lin = (blockIdx.z * 16 + blockIdx.y) * 4 + blockIdx.x;
            const int xcd = lin & 7, j = lin >> 3;        // j in 0..63
            bx = j & 3; by = j >> 2; bz = xcd;            // XCD = batch
        } else { bx = blockIdx.x; by = blockIdx.y; bz = blockIdx.z; }
    }

    const int tid = threadIdx.x;
    const int lane = tid & 63, wav = tid >> 6;
    const int l31 = lane & 31, lh = lane >> 5;
    const int m0 = by * 128, n0 = bx * 128;
    const int bm = (wav >> 1) * 64, bn = (wav & 1) * 64;

    const u16* A = A_ + (size_t)bz * sA;
    const u16* B = B_ + (size_t)bz * sB;

    __shared__ __align__(16) u16 As[8192], Bs[8192];   // 128 x 64 fp16 each

    const int r0 = tid >> 3;
    const int c0 = ((tid & 7) ^ (r0 & 7)) * 8;
    size_t aoff[4], boff[4];
#pragma unroll
    for (int j = 0; j < 4; j++) {
        aoff[j] = (size_t)(m0 + r0 + j * 32) * lda + c0;
        boff[j] = (size_t)(n0 + r0 + j * 32) * ldb + c0;
    }
    const int g7 = l31 & 7;
    const int rowA0 = (bm + l31) * 64, rowA1 = (bm + 32 + l31) * 64;
    const int rowB0 = (bn + l31) * 64, rowB1 = (bn + 32 + l31) * 64;

    f32x16 acc[2][2];
#pragma unroll
    for (int i = 0; i < 2; i++)
#pragma unroll
        for (int j = 0; j < 2; j++)
#pragma unroll
            for (int r = 0; r < 16; r++) acc[i][j][r] = 0.f;

    for (int k0 = 0; k0 < K; k0 += 64) {
#pragma unroll
        for (int j = 0; j < 4; j++) {
            gl16(A + aoff[j] + k0, As + j * 2048 + wav * 512);
            gl16(B + boff[j] + k0, Bs + j * 2048 + wav * 512);
        }
        __syncthreads();

#pragma unroll
        for (int h = 0; h < 4; h++) {
            const int so = ((h * 2 + lh) ^ g7) * 8;
            f16x8 af[2], bfr[2];
            af[0] = *(const f16x8*)&As[rowA0 + so];
            af[1] = *(const f16x8*)&As[rowA1 + so];
            bfr[0] = *(const f16x8*)&Bs[rowB0 + so];
            bfr[1] = *(const f16x8*)&Bs[rowB1 + so];
#pragma unroll
            for (int i = 0; i < 2; i++)
#pragma unroll
                for (int j = 0; j < 2; j++)
                    acc[i][j] = mfma16(af[i], bfr[j], acc[i][j]);
        }
        __syncthreads();
    }

    // ---- epilogue: 32x32 C/D layout col=lane&31, row=(r&3)+8*(r>>2)+4*lh ----
    if (EPI == 2) {
        const int mode = bx >> 2;   // 0=q 1=k 2=v
#pragma unroll
        for (int it = 0; it < 2; it++)
#pragma unroll
            for (int jt = 0; jt < 2; jt++) {
                const int gcol = n0 + bn + jt * 32 + l31;
                const int lcol = gcol & 511;
                const float badd = biasf[gcol];
#pragma unroll
                for (int r = 0; r < 16; r++) {
                    const int row = m0 + bm + it * 32 + (r & 3) + 8 * (r >> 2) + 4 * lh;
                    const float v = acc[it][jt][r] + badd;
                    if (mode == 0)      Oq [(size_t)row * 512 + lcol] = f2h(v);
                    else if (mode == 1) Ok [(size_t)row * 512 + lcol] = f2h(v);
                    else                OvT[(size_t)lcol * 16384 + row] = f2h(v);
                }
            }
    } else if (EPI == 0) {
        float* Cf = (float*)Cp;
        const long coff = (long)bz * sC;
#pragma unroll
        for (int it = 0; it < 2; it++)
#pragma unroll
            for (int jt = 0; jt < 2; jt++) {
                const int col = n0 + bn + jt * 32 + l31;
#pragma unroll
                for (int r = 0; r < 16; r++) {
                    const int row = m0 + bm + it * 32 + (r & 3) + 8 * (r >> 2) + 4 * lh;
                    Cf[(size_t)(coff + (long)row * ldc + col)] = acc[it][jt][r];
                }
            }
    } else {
        const int isbf = *flagp;
        float* Cf = (float*)Cp;
        u16* Cb = (u16*)Cp;
        const long coff = cbase + (long)bz * sC;
#pragma unroll
        for (int it = 0; it < 2; it++)
#pragma unroll
            for (int jt = 0; jt < 2; jt++) {
                const int col = n0 + bn + jt * 32 + l31;
#pragma unroll
                for (int r = 0; r < 16; r++) {
                    const int row = m0 + bm + it * 32 + (r & 3) + 8 * (r >> 2) + 4 * lh;
                    const size_t idx = (size_t)(coff + (long)row * ldc + col);
                    if (isbf) Cb[idx] = f2bf(acc[it][jt][r]);
                    else Cf[idx] = acc[it][jt][r];
                }
            }
    }
}

// ---- softmax: fp32 row -> fp16 P in place (first half of row bytes) ----
__global__ __launch_bounds__(256) void softmax_k(float* __restrict__ sc)
{
    float* srow = sc + (size_t)blockIdx.x * S_LEN;
    const int tid = threadIdx.x;

    float4 a = ((const float4*)srow)[tid];
    float4 b = ((const float4*)srow)[256 + tid];

    float m = fmaxf(fmaxf(fmaxf(a.x, a.y), fmaxf(a.z, a.w)),
                    fmaxf(fmaxf(b.x, b.y), fmaxf(b.z, b.w)));
#pragma unroll
    for (int off = 32; off > 0; off >>= 1) m = fmaxf(m, __shfl_down(m, off));

    __shared__ float redm[4], reds[4];
    if ((tid & 63) == 0) redm[tid >> 6] = m;
    __syncthreads();
    m = fmaxf(fmaxf(redm[0], redm[1]), fmaxf(redm[2], redm[3]));

    a.x = __expf(a.x - m); a.y = __expf(a.y - m);
    a.z = __expf(a.z - m); a.w = __expf(a.w - m);
    b.x = __expf(b.x - m); b.y = __expf(b.y - m);
    b.z = __expf(b.z - m); b.w = __expf(b.w - m);
    float s = a.x + a.y + a.z + a.w + b.x + b.y + b.z + b.w;
#pragma unroll
    for (int off = 32; off > 0; off >>= 1) s += __shfl_down(s, off);
    if ((tid & 63) == 0) reds[tid >> 6] = s;
    __syncthreads();
    s = reds[0] + reds[1] + reds[2] + reds[3];

    const float inv = 1.0f / s;
    ushort4 pa, pb;
    pa.x = f2h(a.x * inv); pa.y = f2h(a.y * inv);
    pa.z = f2h(a.z * inv); pa.w = f2h(a.w * inv);
    pb.x = f2h(b.x * inv); pb.y = f2h(b.y * inv);
    pb.z = f2h(b.z * inv); pb.w = f2h(b.w * inv);
    ((ushort4*)srow)[tid] = pa;
    ((ushort4*)srow)[256 + tid] = pb;
}

extern "C" void kernel_launch(void* const* d_in, const int* in_sizes, int n_in,
                              void* d_out, int out_size, void* d_ws, size_t ws_size,
                              hipStream_t stream)
{
    const void* x  = d_in[0];
    const void* Wq = d_in[1]; const void* bq = d_in[2];
    const void* Wk = d_in[3]; const void* bk = d_in[4];
    const void* Wv = d_in[5]; const void* bv = d_in[6];

    const int S = S_LEN, D = D_DIM;
    const long SD = (long)S * D;                      // 1,048,576

    char* w = (char*)d_ws;
    int*   flag = (int*)w;                            // @0
    u16*   WT   = (u16*)(w + 1024);                   // 1,572,864
    float* bcat = (float*)(w + 1573888);              // 6,144
    u16*   xf   = (u16*)(w + 1580032);                // 16,777,216
    u16*   qf   = (u16*)(w + 18357248);
    u16*   kf   = (u16*)(w + 35134464);
    u16*   vT   = (u16*)(w + 51911680);               // [512][16384]
    float* scA  = (float*)(w + 68688896);             // scores arena

    const size_t avail = ws_size > 68688896ull ? ws_size - 68688896ull : 0;
    const size_t perb = (size_t)S * S * 4;
    const int c = avail >= 8 * perb ? 8 : avail >= 4 * perb ? 4 : avail >= 2 * perb ? 2 : 1;

    dim3 blk(256);

    detect_k<<<1, 64, 0, stream>>>((const u16*)x, flag);
    cvt_x<<<8192, blk, 0, stream>>>(x, xf, flag);
    pack_w<<<dim3(512, 6), blk, 0, stream>>>(Wq, Wk, Wv, WT, flag);
    pack_bias<<<6, blk, 0, stream>>>(bq, bk, bv, bcat, flag);

    // fused q|k|v projection: [16384,512] x [512,1536]^T(packed WT)
    gemm_f16<2><<<dim3(12, 128, 1), blk, 0, stream>>>(
        xf, WT, nullptr, bcat, qf, kf, vT, flag,
        512, 512, 512, 0, 0, 0, 0, 0);

    for (int cb = 0; cb < B_N; cb += c) {
        const size_t off = (size_t)cb * SD;
        // scores = q k^T (fp32)
        gemm_f16<0><<<dim3(16, 16, c), blk, 0, stream>>>(
            qf + off, kf + off, scA, nullptr, nullptr, nullptr, nullptr, flag,
            512, 512, 512, S, SD, SD, (long)S * S, 0);
        softmax_k<<<c * S, blk, 0, stream>>>(scA);
        // out = P @ v via vT rows; P fp16 over fp32 rows (lda = 2S)
        gemm_f16<1><<<dim3(4, 16, c), blk, 0, stream>>>(
            (const u16*)scA, vT + (size_t)cb * S, d_out, nullptr,
            nullptr, nullptr, nullptr, flag,
            S, 2 * S, B_N * S, D, 2ll * S * S, S, SD, (long)cb * SD);
    }
}